// Round 3
// baseline (710.763 us; speedup 1.0000x reference)
//
#include <hip/hip_runtime.h>
#include <hip/hip_bf16.h>

#define NF 40960
#define MD 256
#define BATCH 2048
#define ROWS (2 * BATCH)          // 4096 (pos,color) rows
#define CAPW 48                   // per-wave nonzero list cap (mean 8)

#define TRANS_BLOCKS ((NF / 64) * (MD / 64))      // 2560
#define SCAN_BLOCKS ROWS                          // 4096

__device__ __forceinline__ float clip01(float v) {
    return fminf(fmaxf(v, 0.0f), 1.0f);
}

// ---------------------------------------------------------------------------
// Kernel 1: ft_w transpose (blocks 0..TRANS) + pipelined sparse scan
// (blocks TRANS..TRANS+ROWS). Scan: one block per (pos,color) row, each of
// the 4 waves owns a private nonzero list (no __syncthreads on scan path).
// Register double-buffer keeps 4 float4 loads in flight through the tests
// -> compiler emits partial vmcnt waits instead of vmcnt(0) drains.
// ---------------------------------------------------------------------------
__global__ __launch_bounds__(256) void scan_transpose(
    const float* __restrict__ wf, const float* __restrict__ bfeat,
    const float* __restrict__ ft_w,
    float* __restrict__ ftT, int* __restrict__ g_cnt, int* __restrict__ g_idx)
{
    __shared__ float tile[64][65];        // transpose path (16.6 KB)
    __shared__ int s_cnt[4];
    __shared__ int s_idx[4][CAPW];

    const int b = blockIdx.x;
    const int t = threadIdx.x;

    if (b < TRANS_BLOCKS) {
        // ---- transpose one 64x64 tile: ft_w [256,40960] -> ftT [40960,256]
        const int f0 = (b % (NF / 64)) * 64;
        const int m0 = (b / (NF / 64)) * 64;
        const int tx = t & 63;
        const int ty = t >> 6;
        #pragma unroll
        for (int r = ty; r < 64; r += 4)
            tile[r][tx] = ft_w[(size_t)(m0 + r) * NF + f0 + tx];
        __syncthreads();
        #pragma unroll
        for (int r = ty; r < 64; r += 4)
            ftT[(size_t)(f0 + r) * MD + m0 + tx] = tile[tx][r];
        return;
    }

    // ---- pipelined sparse scan of one (pos,color) row (160 KB) ----
    const int r     = b - TRANS_BLOCKS;   // 0..4095
    const int color = r & 1;
    const int pos   = r >> 1;
    const int w     = t >> 6;             // wave id 0..3
    const int lane  = t & 63;

    if (lane == 0) s_cnt[w] = 0;          // wave-private; DS ops in-order per wave

    const float4* p4 = (const float4*)((color ? bfeat : wf) + (size_t)pos * NF);

    float4 buf[2][4];
    #pragma unroll
    for (int i = 0; i < 4; ++i) buf[0][i] = p4[t + 256 * i];

    #pragma unroll
    for (int bb = 0; bb < 10; ++bb) {
        const int cur = bb & 1, nxt = cur ^ 1;
        if (bb < 9) {
            #pragma unroll
            for (int i = 0; i < 4; ++i)
                buf[nxt][i] = p4[t + 256 * (4 * (bb + 1) + i)];
        }
        #pragma unroll
        for (int i = 0; i < 4; ++i) {
            float4 a = buf[cur][i];
            if (a.x + a.y + a.z + a.w != 0.0f) {      // values are exactly 0/1
                const int nz = (a.x != 0.0f) + (a.y != 0.0f) +
                               (a.z != 0.0f) + (a.w != 0.0f);
                int q = atomicAdd(&s_cnt[w], nz);
                const int col = 4 * (t + 256 * (4 * bb + i));
                if (a.x != 0.0f) { if (q < CAPW) s_idx[w][q] = col;     ++q; }
                if (a.y != 0.0f) { if (q < CAPW) s_idx[w][q] = col + 1; ++q; }
                if (a.z != 0.0f) { if (q < CAPW) s_idx[w][q] = col + 2; ++q; }
                if (a.w != 0.0f) { if (q < CAPW) s_idx[w][q] = col + 3; ++q; }
            }
        }
    }

    const int c = min(s_cnt[w], CAPW);    // same-wave DS ordering guarantees ready
    if (lane == 0) g_cnt[r * 4 + w] = c;
    if (lane < c)  g_idx[(size_t)(r * 4 + w) * CAPW + lane] = s_idx[w][lane];
}

// ---------------------------------------------------------------------------
// Kernel 2: per-position gather (float4-wide, 4 waves x 2 chains) + MLP tail.
// ---------------------------------------------------------------------------
__global__ __launch_bounds__(256) void gather_mlp(
    const float* __restrict__ stm, const float* __restrict__ ftT,
    const int* __restrict__ g_cnt, const int* __restrict__ g_idx,
    const float* __restrict__ ft_b,
    const float* __restrict__ l1_w, const float* __restrict__ l1_b,
    const float* __restrict__ l2_w, const float* __restrict__ l2_b,
    const float* __restrict__ l3_w, const float* __restrict__ l3_b,
    float* __restrict__ out)
{
    __shared__ int lw[4 * CAPW], lb[4 * CAPW];
    __shared__ int cnts[8], offs[8];
    __shared__ int cw_s, cb_s;
    __shared__ float4 accw_sh[4][64];
    __shared__ float4 accb_sh[4][64];
    __shared__ float xsh[512];
    __shared__ float red[32][9];
    __shared__ float ysh[32], zsh[32];

    const int pos = blockIdx.x;
    const int t = threadIdx.x;

    // counts: list id = (pos*2 + color)*4 + wave
    if (t < 8) cnts[t] = g_cnt[(pos * 2 + (t >> 2)) * 4 + (t & 3)];
    __syncthreads();
    if (t == 0) {
        int ow = 0, ob = 0;
        #pragma unroll
        for (int c = 0; c < 4; ++c) {
            offs[c]     = ow; ow += cnts[c];
            offs[4 + c] = ob; ob += cnts[4 + c];
        }
        cw_s = ow; cb_s = ob;
    }
    __syncthreads();
    #pragma unroll
    for (int c = 0; c < 4; ++c) {
        if (t < cnts[c])     lw[offs[c] + t]     = g_idx[(size_t)((pos * 2 + 0) * 4 + c) * CAPW + t];
        if (t < cnts[4 + c]) lb[offs[4 + c] + t] = g_idx[(size_t)((pos * 2 + 1) * 4 + c) * CAPW + t];
    }
    __syncthreads();

    const int cw = cw_s, cb = cb_s;
    const int g  = t >> 6;     // wave id: handles rows j == g (mod 4)
    const int c4 = t & 63;     // float4 column within row

    float4 a0 = {0.f, 0.f, 0.f, 0.f}, a1 = {0.f, 0.f, 0.f, 0.f};
    {
        int j = g;
        for (; j + 4 < cw; j += 8) {
            const float4 v0 = ((const float4*)(ftT + (size_t)lw[j]     * MD))[c4];
            const float4 v1 = ((const float4*)(ftT + (size_t)lw[j + 4] * MD))[c4];
            a0.x += v0.x; a0.y += v0.y; a0.z += v0.z; a0.w += v0.w;
            a1.x += v1.x; a1.y += v1.y; a1.z += v1.z; a1.w += v1.w;
        }
        for (; j < cw; j += 4) {
            const float4 v0 = ((const float4*)(ftT + (size_t)lw[j] * MD))[c4];
            a0.x += v0.x; a0.y += v0.y; a0.z += v0.z; a0.w += v0.w;
        }
        a0.x += a1.x; a0.y += a1.y; a0.z += a1.z; a0.w += a1.w;
        accw_sh[g][c4] = a0;
    }
    float4 b0 = {0.f, 0.f, 0.f, 0.f}, b1 = {0.f, 0.f, 0.f, 0.f};
    {
        int j = g;
        for (; j + 4 < cb; j += 8) {
            const float4 v0 = ((const float4*)(ftT + (size_t)lb[j]     * MD))[c4];
            const float4 v1 = ((const float4*)(ftT + (size_t)lb[j + 4] * MD))[c4];
            b0.x += v0.x; b0.y += v0.y; b0.z += v0.z; b0.w += v0.w;
            b1.x += v1.x; b1.y += v1.y; b1.z += v1.z; b1.w += v1.w;
        }
        for (; j < cb; j += 4) {
            const float4 v0 = ((const float4*)(ftT + (size_t)lb[j] * MD))[c4];
            b0.x += v0.x; b0.y += v0.y; b0.z += v0.z; b0.w += v0.w;
        }
        b0.x += b1.x; b0.y += b1.y; b0.z += b1.z; b0.w += b1.w;
        accb_sh[g][c4] = b0;
    }
    __syncthreads();

    // cross-wave reduce: thread t owns channel m = t  (word addr = g2*256 + t)
    float accW = ft_b[t];
    float accB = ft_b[t];
    #pragma unroll
    for (int g2 = 0; g2 < 4; ++g2) {
        accW += ((const float*)&accw_sh[g2][t >> 2])[t & 3];
        accB += ((const float*)&accb_sh[g2][t >> 2])[t & 3];
    }

    // stm perspective select + clip -> x[512]
    const float s = stm[pos];
    xsh[t]       = clip01(s * accW + (1.0f - s) * accB);
    xsh[256 + t] = clip01(s * accB + (1.0f - s) * accW);
    __syncthreads();

    // L1: y[n] = clip(sum_512 x[j]*l1_w[n][j] + b)
    {
        const int n = t & 31;
        const int c = t >> 5;
        const float* w1 = l1_w + (size_t)n * 512 + c * 64;
        const float* xx = xsh + c * 64;
        float p = 0.0f;
        #pragma unroll
        for (int j = 0; j < 64; ++j) p += xx[j] * w1[j];
        red[n][c] = p;
    }
    __syncthreads();
    if (t < 32) {
        float v = l1_b[t];
        #pragma unroll
        for (int c = 0; c < 8; ++c) v += red[t][c];
        ysh[t] = clip01(v);
    }
    __syncthreads();

    // L2
    if (t < 32) {
        float v = l2_b[t];
        const float* w2 = l2_w + t * 32;
        #pragma unroll
        for (int j = 0; j < 32; ++j) v += ysh[j] * w2[j];
        zsh[t] = clip01(v);
    }
    __syncthreads();

    // L3 + output map
    if (t == 0) {
        float v = l3_b[0];
        #pragma unroll
        for (int j = 0; j < 32; ++j) v += zsh[j] * l3_w[j];
        v = clip01(v);
        out[pos] = (v - 0.5f) * 20000.0f;
    }
}

extern "C" void kernel_launch(void* const* d_in, const int* in_sizes, int n_in,
                              void* d_out, int out_size, void* d_ws, size_t ws_size,
                              hipStream_t stream) {
    const float* wf    = (const float*)d_in[0];
    const float* bfeat = (const float*)d_in[1];
    const float* stm   = (const float*)d_in[2];
    const float* ft_w  = (const float*)d_in[3];
    const float* ft_b  = (const float*)d_in[4];
    const float* l1_w  = (const float*)d_in[5];
    const float* l1_b  = (const float*)d_in[6];
    const float* l2_w  = (const float*)d_in[7];
    const float* l2_b  = (const float*)d_in[8];
    const float* l3_w  = (const float*)d_in[9];
    const float* l3_b  = (const float*)d_in[10];
    float* out = (float*)d_out;

    // ws layout: ftT (41.9 MB) | counts (64 KB) | indices (3 MB)
    float* ftT   = (float*)d_ws;
    int*   g_cnt = (int*)((char*)d_ws + (size_t)NF * MD * sizeof(float));
    int*   g_idx = g_cnt + ROWS * 4;

    scan_transpose<<<TRANS_BLOCKS + SCAN_BLOCKS, 256, 0, stream>>>(
        wf, bfeat, ft_w, ftT, g_cnt, g_idx);

    gather_mlp<<<BATCH, 256, 0, stream>>>(
        stm, ftT, g_cnt, g_idx, ft_b,
        l1_w, l1_b, l2_w, l2_b, l3_w, l3_b, out);
}